// Round 1
// baseline (513.725 us; speedup 1.0000x reference)
//
#include <hip/hip_runtime.h>

// Problem: TextCNN. B=128, S=512, VOCAB=50000, E=300, H=64, k_i = i/2+2 in [2,33].
// Strategy: virtual-im2col bf16 MFMA GEMM.
//   e_ws[b][s][EPAD=320] (bf16, 320%32==0) => im2col A[t][kappa] = flat[t*320+kappa].
//   Filters grouped by 16 (group g has k_max = 8g+9, K_g = (8g+9)*320).
//   Weights prepacked in B-fragment order for coalesced 16B/lane loads.
// ws layout: [0, 860160) wsB bf16 | [1MB, ~45.6MB) wsE bf16 | [48MB, +512KB) wsF f32.

#define SS    512
#define EE    300
#define HH    64
#define KMAXW 33
#define EPAD  320
#define SPAD  544          // 512 + 32 zero rows
#define NSTEP 330          // K_3/32 = 33*320/32

typedef __attribute__((ext_vector_type(8))) short bf16x8;
typedef __attribute__((ext_vector_type(4))) float f32x4;

__device__ __forceinline__ unsigned short f2bf(float f) {
    unsigned u = __float_as_uint(f);
    unsigned r = ((u >> 16) & 1u) + 0x7FFFu;   // round-to-nearest-even
    return (unsigned short)((u + r) >> 16);
}

// ---- Kernel 1: repack Wconv (f32 [H][33][300]) -> wsB bf16 in B-fragment order.
// wsB[step*512 + lane*8 + r]; step in [0,840): g bases {0,90,260,510}.
// B-frag: n = lane&15 (filter within group), k = s32*32 + (lane>>4)*8 + r.
__global__ __launch_bounds__(256) void prep_weights(const float* __restrict__ Wconv,
                                                    unsigned short* __restrict__ wsB) {
    int idx = blockIdx.x * 256 + threadIdx.x;      // < 430080
    int r    = idx & 7;
    int lane = (idx >> 3) & 63;
    int step = idx >> 9;
    int g, s32;
    if      (step < 90)  { g = 0; s32 = step;       }
    else if (step < 260) { g = 1; s32 = step - 90;  }
    else if (step < 510) { g = 2; s32 = step - 260; }
    else                 { g = 3; s32 = step - 510; }
    int n = lane & 15, quad = lane >> 4;
    int i  = g * 16 + n;
    int ki = i / 2 + 2;
    int kap = s32 * 32 + quad * 8 + r;
    int j = kap / EPAD;
    int e = kap - j * EPAD;
    float v = 0.f;
    if (e < EE && j < ki) v = Wconv[(i * KMAXW + j) * EE + e];
    wsB[idx] = f2bf(v);
}

// ---- Kernel 2: gather embeddings -> wsE bf16 [128][SPAD][EPAD], zero padded.
__global__ __launch_bounds__(256) void gather_embed(const int* __restrict__ x,
                                                    const float* __restrict__ emb,
                                                    unsigned short* __restrict__ wsE) {
    long idx = (long)blockIdx.x * 256 + threadIdx.x;  // < 128*544*320 = 22282240
    int  e  = (int)(idx % EPAD);
    long rs = idx / EPAD;
    int  s  = (int)(rs % SPAD);
    int  b  = (int)(rs / SPAD);
    float v = 0.f;
    if (s < SS && e < EE) {
        int tok = x[b * SS + s];
        v = emb[(long)tok * EE + e];
    }
    wsE[idx] = f2bf(v);
}

#define MFMA(A, Bf, C) __builtin_amdgcn_mfma_f32_16x16x32_bf16((A), (Bf), (C), 0, 0, 0)

// ---- Kernel 3: the GEMM + tanh + masked max. 512 blocks x 256 thr = 2048 waves.
// Wave = one (b, mt): 32 t-rows (two 16-row MFMA M-tiles) x all 64 filters (4 groups).
__global__ __launch_bounds__(256) void conv_mfma(const unsigned short* __restrict__ wsE,
                                                 const unsigned short* __restrict__ wsB,
                                                 const float* __restrict__ bconv,
                                                 float* __restrict__ wsF) {
    int lane  = threadIdx.x & 63;
    int w     = threadIdx.x >> 6;
    int gwave = blockIdx.x * 4 + w;        // 0..2047
    int b     = gwave >> 4;                // 0..127
    int mt    = gwave & 15;                // 0..15
    int t0    = mt * 32;
    int m = lane & 15, quad = lane >> 4;

    const unsigned short* eA = wsE + (size_t)b * (SPAD * EPAD)
                                   + (size_t)(t0 + m) * EPAD + quad * 8;
    const unsigned short* bp = wsB + lane * 8;

    f32x4 acc[2][4] = {};

    for (int s = 0; s < NSTEP; ++s) {
        int ko = s * 32;
        bf16x8 a0 = *(const bf16x8*)(eA + ko);
        bf16x8 a1 = *(const bf16x8*)(eA + 16 * EPAD + ko);
        {   // group 3 (always active)
            bf16x8 bf = *(const bf16x8*)(bp + (size_t)(510 + s) * 512);
            acc[0][3] = MFMA(a0, bf, acc[0][3]);
            acc[1][3] = MFMA(a1, bf, acc[1][3]);
        }
        if (s < 250) {
            bf16x8 bf = *(const bf16x8*)(bp + (size_t)(260 + s) * 512);
            acc[0][2] = MFMA(a0, bf, acc[0][2]);
            acc[1][2] = MFMA(a1, bf, acc[1][2]);
        }
        if (s < 170) {
            bf16x8 bf = *(const bf16x8*)(bp + (size_t)(90 + s) * 512);
            acc[0][1] = MFMA(a0, bf, acc[0][1]);
            acc[1][1] = MFMA(a1, bf, acc[1][1]);
        }
        if (s < 90) {
            bf16x8 bf = *(const bf16x8*)(bp + (size_t)s * 512);
            acc[0][0] = MFMA(a0, bf, acc[0][0]);
            acc[1][0] = MFMA(a1, bf, acc[1][0]);
        }
    }

    // Epilogue: C/D layout col=lane&15 (filter), row=quad*4+reg (t offset).
    for (int g = 0; g < 4; ++g) {
        int i  = g * 16 + m;
        int ki = i / 2 + 2;
        int tmax = SS - ki;                 // valid t <= tmax
        float bc = bconv[i];
        float mx = -3.0e38f;
        #pragma unroll
        for (int a = 0; a < 2; ++a) {
            int tb = t0 + a * 16 + quad * 4;
            #pragma unroll
            for (int r = 0; r < 4; ++r) {
                float v = tanhf(acc[a][g][r] + bc);
                if (tb + r <= tmax) mx = fmaxf(mx, v);
            }
        }
        mx = fmaxf(mx, __shfl_xor(mx, 16));
        mx = fmaxf(mx, __shfl_xor(mx, 32));
        if (quad == 0) wsF[(b * HH + i) * 16 + mt] = mx;
    }
}

// ---- Kernel 4: max over tiles, linear, sigmoid.
__global__ __launch_bounds__(128) void final_linear(const float* __restrict__ wsF,
                                                    const float* __restrict__ Wlin,
                                                    const float* __restrict__ blin,
                                                    float* __restrict__ out) {
    int b = threadIdx.x;                   // single block of 128
    float s = blin[0];
    for (int i = 0; i < HH; ++i) {
        const float* p = wsF + (b * HH + i) * 16;
        float mx = p[0];
        #pragma unroll
        for (int j = 1; j < 16; ++j) mx = fmaxf(mx, p[j]);
        s += mx * Wlin[i];
    }
    out[b] = 1.0f / (1.0f + expf(-s));
}

extern "C" void kernel_launch(void* const* d_in, const int* in_sizes, int n_in,
                              void* d_out, int out_size, void* d_ws, size_t ws_size,
                              hipStream_t stream) {
    const int*   x     = (const int*)d_in[0];
    const float* emb   = (const float*)d_in[1];
    const float* Wconv = (const float*)d_in[2];
    const float* bconv = (const float*)d_in[3];
    const float* Wlin  = (const float*)d_in[4];
    const float* blin  = (const float*)d_in[5];
    float* out = (float*)d_out;

    unsigned short* wsB = (unsigned short*)d_ws;
    unsigned short* wsE = (unsigned short*)((char*)d_ws + (1u << 20));
    float*          wsF = (float*)((char*)d_ws + (48u << 20));

    prep_weights<<<430080 / 256, 256, 0, stream>>>(Wconv, wsB);
    gather_embed<<<(128 * SPAD * EPAD) / 256, 256, 0, stream>>>(x, emb, wsE);
    conv_mfma<<<512, 256, 0, stream>>>(wsE, wsB, bconv, wsF);
    final_linear<<<1, 128, 0, stream>>>(wsF, Wlin, blin, out);
}

// Round 2
// 334.399 us; speedup vs baseline: 1.5363x; 1.5363x over previous
//
#include <hip/hip_runtime.h>

// TextCNN: B=128, S=512, E=300, H=64, k_i = i/2+2 in [2,33].
// Virtual-im2col bf16 MFMA GEMM with block-level LDS staging of the A panel.
//   wsE[b][s][EPAD=320] bf16 => im2col A[t][kappa] = flat[t*320+kappa].
//   Filter groups of 16: group g K-steps = {90,170,250,330} (multiples of 10).
//   conv block = 4 waves x 16 t-rows = 64 rows + 32 halo staged in LDS
//   (row stride 328 elems = 656 B: 16B-aligned, 2-way bank aliasing = free).
// ws layout: [0, 860KB) wsB bf16 | [1MB, 45.6MB) wsE bf16 | [46MB, +1MB) wsF f32.

#define SS    512
#define EE    300
#define HH    64
#define KMAXW 33
#define EPAD  320
#define SPAD  544
#define LROWS 96
#define LPITCH 328

typedef __attribute__((ext_vector_type(8))) short bf16x8;
typedef __attribute__((ext_vector_type(4))) float f32x4;

__device__ __forceinline__ unsigned short f2bf(float f) {
    unsigned u = __float_as_uint(f);
    unsigned r = ((u >> 16) & 1u) + 0x7FFFu;   // round-to-nearest-even
    return (unsigned short)((u + r) >> 16);
}

// ---- Kernel 1: repack Wconv (f32 [H][33][300]) -> wsB bf16 in B-fragment order.
// wsB[step*512 + lane*8 + r]; step in [0,840): group bases {0,90,260,510}.
__global__ __launch_bounds__(256) void prep_weights(const float* __restrict__ Wconv,
                                                    unsigned short* __restrict__ wsB) {
    int idx = blockIdx.x * 256 + threadIdx.x;      // < 430080
    int r    = idx & 7;
    int lane = (idx >> 3) & 63;
    int step = idx >> 9;
    int g, s32;
    if      (step < 90)  { g = 0; s32 = step;       }
    else if (step < 260) { g = 1; s32 = step - 90;  }
    else if (step < 510) { g = 2; s32 = step - 260; }
    else                 { g = 3; s32 = step - 510; }
    int n = lane & 15, quad = lane >> 4;
    int i  = g * 16 + n;
    int ki = i / 2 + 2;
    int kap = s32 * 32 + quad * 8 + r;
    int j = kap / EPAD;
    int e = kap - j * EPAD;
    float v = 0.f;
    if (e < EE && j < ki) v = Wconv[(i * KMAXW + j) * EE + e];
    wsB[idx] = f2bf(v);
}

// ---- Kernel 2: gather embeddings -> wsE bf16 [128][544][320], 16B per thread.
__global__ __launch_bounds__(256) void gather_embed(const int* __restrict__ x,
                                                    const float* __restrict__ emb,
                                                    unsigned short* __restrict__ wsE) {
    int idx = blockIdx.x * 256 + threadIdx.x;   // < 128*544*40 = 2785280
    int c  = idx % 40;
    int rs = idx / 40;
    int s  = rs % SPAD;
    int b  = rs / SPAD;
    bf16x8 v = {0, 0, 0, 0, 0, 0, 0, 0};
    if (s < SS && c < 38) {
        int tok = x[b * SS + s];
        const float4* ep = (const float4*)(emb + (long)tok * EE + c * 8);
        float4 f0 = ep[0];
        v[0] = f2bf(f0.x); v[1] = f2bf(f0.y); v[2] = f2bf(f0.z); v[3] = f2bf(f0.w);
        if (c < 37) {
            float4 f1 = ep[1];
            v[4] = f2bf(f1.x); v[5] = f2bf(f1.y); v[6] = f2bf(f1.z); v[7] = f2bf(f1.w);
        }
    }
    ((bf16x8*)wsE)[idx] = v;
}

#define MFMA(A, Bf, C) __builtin_amdgcn_mfma_f32_16x16x32_bf16((A), (Bf), (C), 0, 0, 0)

template<int NG>
__device__ __forceinline__ void do_j(const unsigned short* lrow,
                                     const unsigned short* __restrict__ bp,
                                     int s0, f32x4* acc) {
    #pragma unroll
    for (int sj = 0; sj < 10; ++sj) {
        int s = s0 + sj;
        bf16x8 a = *(const bf16x8*)(lrow + sj * 32);
        acc[3] = MFMA(a, *(const bf16x8*)(bp + (510 + s) * 512), acc[3]);
        if (NG >= 2) acc[2] = MFMA(a, *(const bf16x8*)(bp + (260 + s) * 512), acc[2]);
        if (NG >= 3) acc[1] = MFMA(a, *(const bf16x8*)(bp + (90 + s) * 512), acc[1]);
        if (NG >= 4) acc[0] = MFMA(a, *(const bf16x8*)(bp + s * 512), acc[0]);
    }
}

// ---- Kernel 3: GEMM + tanh + masked max. 1024 blocks x 256 thr.
// Block = (b, quarter): 64 t-rows; wave w handles rows t0+w*16..+15, all 64 filters.
__global__ __launch_bounds__(256) void conv_mfma(const unsigned short* __restrict__ wsE,
                                                 const unsigned short* __restrict__ wsB,
                                                 const float* __restrict__ bconv,
                                                 float* __restrict__ wsF) {
    __shared__ __align__(16) unsigned short Atile[LROWS * LPITCH];

    int b       = blockIdx.x >> 3;
    int quarter = blockIdx.x & 7;
    int t0      = quarter * 64;

    // Stage 96 rows x 320 elems (block's 64 rows + 32 halo; SPAD=544 covers it).
    const unsigned short* src = wsE + (size_t)b * (SPAD * EPAD) + (size_t)t0 * EPAD;
    for (int idx = threadIdx.x; idx < LROWS * 40; idx += 256) {
        int r = idx / 40, c = idx - r * 40;
        *(bf16x8*)&Atile[r * LPITCH + c * 8] = *(const bf16x8*)(src + r * EPAD + c * 8);
    }
    __syncthreads();

    int lane = threadIdx.x & 63;
    int w    = threadIdx.x >> 6;
    int m = lane & 15, q = lane >> 4;

    const unsigned short* lbase = Atile + (w * 16 + m) * LPITCH + q * 8;
    const unsigned short* bp    = wsB + lane * 8;

    f32x4 acc[4] = {};
    int s = 0;
    #pragma unroll 1
    for (int j = 0;  j < 9;  ++j, s += 10) do_j<4>(lbase + j * LPITCH, bp, s, acc);
    #pragma unroll 1
    for (int j = 9;  j < 17; ++j, s += 10) do_j<3>(lbase + j * LPITCH, bp, s, acc);
    #pragma unroll 1
    for (int j = 17; j < 25; ++j, s += 10) do_j<2>(lbase + j * LPITCH, bp, s, acc);
    #pragma unroll 1
    for (int j = 25; j < 33; ++j, s += 10) do_j<1>(lbase + j * LPITCH, bp, s, acc);

    // Epilogue: C/D col = lane&15 (filter), row = q*4+reg (t offset).
    int tb = t0 + w * 16 + q * 4;
    for (int g = 0; g < 4; ++g) {
        int i  = g * 16 + m;
        int ki = i / 2 + 2;
        int tmax = SS - ki;
        float bc = bconv[i];
        float mx = -3.0e38f;
        #pragma unroll
        for (int r = 0; r < 4; ++r) {
            float v = tanhf(acc[g][r] + bc);
            if (tb + r <= tmax) mx = fmaxf(mx, v);
        }
        mx = fmaxf(mx, __shfl_xor(mx, 16));
        mx = fmaxf(mx, __shfl_xor(mx, 32));
        if (q == 0) wsF[(b * HH + i) * 32 + quarter * 4 + w] = mx;
    }
}

// ---- Kernel 4: max over 32 tiles, linear, sigmoid.
__global__ __launch_bounds__(128) void final_linear(const float* __restrict__ wsF,
                                                    const float* __restrict__ Wlin,
                                                    const float* __restrict__ blin,
                                                    float* __restrict__ out) {
    int b = threadIdx.x;                   // single block of 128
    float s = blin[0];
    for (int i = 0; i < HH; ++i) {
        const float* p = wsF + (b * HH + i) * 32;
        float mx = p[0];
        #pragma unroll
        for (int j = 1; j < 32; ++j) mx = fmaxf(mx, p[j]);
        s += mx * Wlin[i];
    }
    out[b] = 1.0f / (1.0f + expf(-s));
}

extern "C" void kernel_launch(void* const* d_in, const int* in_sizes, int n_in,
                              void* d_out, int out_size, void* d_ws, size_t ws_size,
                              hipStream_t stream) {
    const int*   x     = (const int*)d_in[0];
    const float* emb   = (const float*)d_in[1];
    const float* Wconv = (const float*)d_in[2];
    const float* bconv = (const float*)d_in[3];
    const float* Wlin  = (const float*)d_in[4];
    const float* blin  = (const float*)d_in[5];
    float* out = (float*)d_out;

    unsigned short* wsB = (unsigned short*)d_ws;
    unsigned short* wsE = (unsigned short*)((char*)d_ws + (1u << 20));
    float*          wsF = (float*)((char*)d_ws + (46u << 20));

    prep_weights<<<430080 / 256, 256, 0, stream>>>(Wconv, wsB);
    gather_embed<<<(128 * SPAD * 40) / 256, 256, 0, stream>>>(x, emb, wsE);
    conv_mfma<<<1024, 256, 0, stream>>>(wsE, wsB, bconv, wsF);
    final_linear<<<1, 128, 0, stream>>>(wsF, Wlin, blin, out);
}

// Round 3
// 277.088 us; speedup vs baseline: 1.8540x; 1.2068x over previous
//
#include <hip/hip_runtime.h>

// TextCNN: B=128, S=512, E=300, H=64, k_i = i/2+2 in [2,33].
// Virtual-im2col bf16 MFMA GEMM, fused gather, wave-specialized group halves.
//   Block = (b, quarter): 128 t-rows + 32 halo staged in LDS (f32->bf16 inline).
//   Wave (p,h): p = M-half (4 tiles of 16 rows), h = group half {3,0} / {2,1}.
//   B-frags (wsB, 860KB, prepacked fragment order) stream via L1/L2, reused x4.
// ws layout: [0, 860KB) wsB bf16 | [1MB, 2MB) wsF f32 (128*64*32).

#define SS     512
#define EE     300
#define HH     64
#define KMAXW  33
#define LROWS  160
#define LPITCH 328          // elems; 656 B row pitch (16B-aligned, 2-way bank alias)

typedef __attribute__((ext_vector_type(8))) short bf16x8;
typedef __attribute__((ext_vector_type(4))) float f32x4;

__device__ __forceinline__ unsigned short f2bf(float f) {
    unsigned u = __float_as_uint(f);
    unsigned r = ((u >> 16) & 1u) + 0x7FFFu;   // round-to-nearest-even
    return (unsigned short)((u + r) >> 16);
}

// ---- Kernel 1: repack Wconv (f32 [64][33][300]) -> wsB bf16, B-fragment order.
// wsB[step*512 + lane*8 + r]; steps: g0 [0,90) g1 [90,260) g2 [260,510) g3 [510,840).
__global__ __launch_bounds__(256) void prep_weights(const float* __restrict__ Wconv,
                                                    unsigned short* __restrict__ wsB) {
    int idx = blockIdx.x * 256 + threadIdx.x;      // < 430080
    int r    = idx & 7;
    int lane = (idx >> 3) & 63;
    int step = idx >> 9;
    int g, s32;
    if      (step < 90)  { g = 0; s32 = step;       }
    else if (step < 260) { g = 1; s32 = step - 90;  }
    else if (step < 510) { g = 2; s32 = step - 260; }
    else                 { g = 3; s32 = step - 510; }
    int n = lane & 15, quad = lane >> 4;
    int i  = g * 16 + n;
    int ki = i / 2 + 2;
    int kap = s32 * 32 + quad * 8 + r;
    int j = kap / 320;
    int e = kap - j * 320;
    float v = 0.f;
    if (e < EE && j < ki) v = Wconv[(i * KMAXW + j) * EE + e];
    wsB[idx] = f2bf(v);
}

#define MFMA(A, Bf, C) __builtin_amdgcn_mfma_f32_16x16x32_bf16((A), (Bf), (C), 0, 0, 0)

template<bool SEC, int PB, int SB>
__device__ __forceinline__ void do10(const unsigned short* lb, int j,
                                     const unsigned short* __restrict__ bp,
                                     f32x4 acc[4][2]) {
    #pragma unroll
    for (int sj = 0; sj < 10; ++sj) {
        int s = j * 10 + sj;
        const unsigned short* lr = lb + j * LPITCH + sj * 32;
        bf16x8 a0 = *(const bf16x8*)(lr);
        bf16x8 a1 = *(const bf16x8*)(lr + 16 * LPITCH);
        bf16x8 a2 = *(const bf16x8*)(lr + 32 * LPITCH);
        bf16x8 a3 = *(const bf16x8*)(lr + 48 * LPITCH);
        bf16x8 bP = *(const bf16x8*)(bp + (PB + s) * 512);
        acc[0][0] = MFMA(a0, bP, acc[0][0]);
        acc[1][0] = MFMA(a1, bP, acc[1][0]);
        acc[2][0] = MFMA(a2, bP, acc[2][0]);
        acc[3][0] = MFMA(a3, bP, acc[3][0]);
        if (SEC) {
            bf16x8 bS = *(const bf16x8*)(bp + (SB + s) * 512);
            acc[0][1] = MFMA(a0, bS, acc[0][1]);
            acc[1][1] = MFMA(a1, bS, acc[1][1]);
            acc[2][1] = MFMA(a2, bS, acc[2][1]);
            acc[3][1] = MFMA(a3, bS, acc[3][1]);
        }
    }
}

// ---- Kernel 2: fused gather + GEMM + tanh + masked max. 512 blocks x 256 thr.
__global__ __launch_bounds__(256) void conv_fused(const int* __restrict__ x,
                                                  const float* __restrict__ emb,
                                                  const unsigned short* __restrict__ wsB,
                                                  const float* __restrict__ bconv,
                                                  float* __restrict__ wsF) {
    __shared__ __align__(16) unsigned short Atile[LROWS * LPITCH];

    int b       = blockIdx.x >> 2;
    int quarter = blockIdx.x & 3;
    int t0      = quarter * 128;

    // Stage 160 rows (128 + 32 halo) of embeddings, f32 -> bf16, zero-padded.
    #pragma unroll
    for (int it = 0; it < 25; ++it) {
        int idx = threadIdx.x + it * 256;          // < 6400
        int r = idx / 40, c = idx - r * 40;
        int srow = t0 + r;
        bf16x8 v = {0, 0, 0, 0, 0, 0, 0, 0};
        if (srow < SS && c < 38) {
            int tok = x[b * SS + srow];
            const float4* ep = (const float4*)(emb + (long)tok * EE + c * 8);
            float4 f0 = ep[0];
            v[0] = f2bf(f0.x); v[1] = f2bf(f0.y); v[2] = f2bf(f0.z); v[3] = f2bf(f0.w);
            if (c < 37) {
                float4 f1 = ep[1];
                v[4] = f2bf(f1.x); v[5] = f2bf(f1.y); v[6] = f2bf(f1.z); v[7] = f2bf(f1.w);
            }
        }
        *(bf16x8*)&Atile[r * LPITCH + c * 8] = v;
    }
    __syncthreads();

    int lane = threadIdx.x & 63;
    int w    = threadIdx.x >> 6;
    int p    = w >> 1;                 // M-half: 4 tiles of 16 rows
    int h    = w & 1;                  // group half: 0 -> {3,0}, 1 -> {2,1}
    int m = lane & 15, q = lane >> 4;

    const unsigned short* lb = Atile + (p * 64 + m) * LPITCH + q * 8;
    const unsigned short* bp = wsB + lane * 8;

    f32x4 acc[4][2] = {};
    if (h == 0) {
        #pragma unroll 1
        for (int j = 0; j < 9;  ++j) do10<true , 510, 0>(lb, j, bp, acc);
        #pragma unroll 1
        for (int j = 9; j < 33; ++j) do10<false, 510, 0>(lb, j, bp, acc);
    } else {
        #pragma unroll 1
        for (int j = 0;  j < 17; ++j) do10<true , 260, 90>(lb, j, bp, acc);
        #pragma unroll 1
        for (int j = 17; j < 25; ++j) do10<false, 260, 90>(lb, j, bp, acc);
    }

    // Epilogue: C/D col = lane&15 (filter within group), row = q*4 + reg.
    int gid[2]; gid[0] = h ? 2 : 3; gid[1] = h ? 1 : 0;
    #pragma unroll
    for (int t = 0; t < 4; ++t) {
        int tb = t0 + p * 64 + t * 16 + q * 4;
        #pragma unroll
        for (int u = 0; u < 2; ++u) {
            int i  = gid[u] * 16 + m;
            int ki = i / 2 + 2;
            int tmax = SS - ki;
            float bc = bconv[i];
            float mx = -3.0e38f;
            #pragma unroll
            for (int r = 0; r < 4; ++r) {
                float v = tanhf(acc[t][u][r] + bc);
                if (tb + r <= tmax) mx = fmaxf(mx, v);
            }
            mx = fmaxf(mx, __shfl_xor(mx, 16));
            mx = fmaxf(mx, __shfl_xor(mx, 32));
            if (q == 0) wsF[(b * HH + i) * 32 + quarter * 8 + p * 4 + t] = mx;
        }
    }
}

// ---- Kernel 3: max over 32 tiles, linear, sigmoid. 128 blocks x 64 thr.
__global__ __launch_bounds__(64) void final_linear(const float* __restrict__ wsF,
                                                   const float* __restrict__ Wlin,
                                                   const float* __restrict__ blin,
                                                   float* __restrict__ out) {
    int b = blockIdx.x;
    int i = threadIdx.x;
    const float4* pp = (const float4*)(wsF + (b * HH + i) * 32);
    float mx = -3.0e38f;
    #pragma unroll
    for (int j = 0; j < 8; ++j) {
        float4 f = pp[j];
        mx = fmaxf(mx, fmaxf(fmaxf(f.x, f.y), fmaxf(f.z, f.w)));
    }
    float v = mx * Wlin[i];
    #pragma unroll
    for (int off = 1; off < 64; off <<= 1) v += __shfl_xor(v, off);
    if (i == 0) out[b] = 1.0f / (1.0f + expf(-(v + blin[0])));
}

extern "C" void kernel_launch(void* const* d_in, const int* in_sizes, int n_in,
                              void* d_out, int out_size, void* d_ws, size_t ws_size,
                              hipStream_t stream) {
    const int*   x     = (const int*)d_in[0];
    const float* emb   = (const float*)d_in[1];
    const float* Wconv = (const float*)d_in[2];
    const float* bconv = (const float*)d_in[3];
    const float* Wlin  = (const float*)d_in[4];
    const float* blin  = (const float*)d_in[5];
    float* out = (float*)d_out;

    unsigned short* wsB = (unsigned short*)d_ws;
    float*          wsF = (float*)((char*)d_ws + (1u << 20));

    prep_weights<<<1680, 256, 0, stream>>>(Wconv, wsB);
    conv_fused<<<512, 256, 0, stream>>>(x, emb, wsB, bconv, wsF);
    final_linear<<<128, 64, 0, stream>>>(wsF, Wlin, blin, out);
}

// Round 4
// 195.167 us; speedup vs baseline: 2.6322x; 1.4198x over previous
//
#include <hip/hip_runtime.h>

// TextCNN: B=128, S=512, E=300, H=64, k_i = i/2+2 in [2,33].
// Virtual-im2col bf16 MFMA GEMM, fused gather, E-split LDS staging for occupancy.
//   Grid: 128 b x 6 t-slices (96 rows each) = 768 blocks = 3/CU resident.
//   Block: 4 waves; wave (p,h) = 3 M-tiles (48 rows) x 2 filter groups.
//   LDS: 128 rows x 168-elem half-rows (336 B) = 42 KB -> 3 blocks/CU, 3 waves/SIMD.
//   K runs over (ehalf, j, u): acc persists across halves (register K-split).
//   wsB prepacked [half][group][j*5+u] in B-fragment order; group bases {0,45,130,255}.
// ws layout: [0, 860KB) wsB bf16 | [1MB, +1.2MB) wsF f32 (128*64*36).

#define SS     512
#define EE     300
#define HH     64
#define KMAXW  33
#define LP     168          // LDS half-row pitch in elems (336 B)
#define HALFSZ 215040       // wsB elems per E-half (420 steps * 512)

typedef __attribute__((ext_vector_type(8))) short bf16x8;
typedef __attribute__((ext_vector_type(4))) float f32x4;

__device__ __forceinline__ unsigned short f2bf(float f) {
    unsigned u = __float_as_uint(f);
    unsigned r = ((u >> 16) & 1u) + 0x7FFFu;   // round-to-nearest-even
    return (unsigned short)((u + r) >> 16);
}

// ---- Kernel 1: repack Wconv (f32 [64][33][300]) -> wsB bf16, fragment order.
// step id within (half, group): j*5+u, u indexes 32-elem sub-blocks of the 160-elem half.
__global__ __launch_bounds__(256) void prep_weights(const float* __restrict__ Wconv,
                                                    unsigned short* __restrict__ wsB) {
    int idx = blockIdx.x * 256 + threadIdx.x;      // < 430080
    int r    = idx & 7;
    int lane = (idx >> 3) & 63;
    int gs   = idx >> 9;                           // < 840
    int h    = gs / 420;
    int ww   = gs - h * 420;
    int g, t;
    if      (ww < 45)  { g = 0; t = ww;       }
    else if (ww < 130) { g = 1; t = ww - 45;  }
    else if (ww < 255) { g = 2; t = ww - 130; }
    else               { g = 3; t = ww - 255; }
    int j = t / 5, u = t - j * 5;
    int i  = g * 16 + (lane & 15);
    int ki = i / 2 + 2;
    int kk = (lane >> 4) * 8 + r;
    int e  = h * 160 + u * 32 + kk;
    float v = 0.f;
    if (e < EE && j < ki) v = Wconv[(i * KMAXW + j) * EE + e];
    wsB[idx] = f2bf(v);
}

#define MFMA(A, Bf, C) __builtin_amdgcn_mfma_f32_16x16x32_bf16((A), (Bf), (C), 0, 0, 0)

template<bool SEC>
__device__ __forceinline__ void do5(const unsigned short* lb, int j,
                                    const unsigned short* __restrict__ bp,
                                    int pbase, int sbase, f32x4 acc[3][2]) {
    #pragma unroll
    for (int u = 0; u < 5; ++u) {
        const unsigned short* lr = lb + j * LP + u * 32;
        bf16x8 a0 = *(const bf16x8*)(lr);
        bf16x8 a1 = *(const bf16x8*)(lr + 16 * LP);
        bf16x8 a2 = *(const bf16x8*)(lr + 32 * LP);
        bf16x8 bP = *(const bf16x8*)(bp + (pbase + j * 5 + u) * 512);
        acc[0][0] = MFMA(a0, bP, acc[0][0]);
        acc[1][0] = MFMA(a1, bP, acc[1][0]);
        acc[2][0] = MFMA(a2, bP, acc[2][0]);
        if (SEC) {
            bf16x8 bS = *(const bf16x8*)(bp + (sbase + j * 5 + u) * 512);
            acc[0][1] = MFMA(a0, bS, acc[0][1]);
            acc[1][1] = MFMA(a1, bS, acc[1][1]);
            acc[2][1] = MFMA(a2, bS, acc[2][1]);
        }
    }
}

// ---- Kernel 2: fused gather + GEMM + tanh + masked max. 768 blocks x 256 thr.
__global__ __launch_bounds__(256, 3) void conv_fused(const int* __restrict__ x,
                                                     const float* __restrict__ emb,
                                                     const unsigned short* __restrict__ wsB,
                                                     const float* __restrict__ bconv,
                                                     float* __restrict__ wsF) {
    __shared__ __align__(16) unsigned short At[128 * LP];   // 42 KB

    int b     = blockIdx.x / 6;
    int slice = blockIdx.x - b * 6;
    int t0    = slice * 96;

    int lane = threadIdx.x & 63;
    int w    = threadIdx.x >> 6;
    int p    = w >> 1;                 // M-half: 3 tiles of 16 rows
    int h2   = w & 1;                  // group half: 0 -> {3,0}, 1 -> {2,1}
    int m = lane & 15, q = lane >> 4;

    f32x4 acc[3][2] = {};

    const unsigned short* lb = At + (p * 48 + m) * LP + q * 8;

    for (int eh = 0; eh < 2; ++eh) {
        if (eh) __syncthreads();       // all reads of previous half complete

        // Stage 128 half-rows (96 + 32 halo), f32 -> bf16, zero-padded.
        #pragma unroll
        for (int it = 0; it < 10; ++it) {
            int idx = threadIdx.x + it * 256;      // < 2560
            int rr = idx / 20, c = idx - rr * 20;
            int srow = t0 + rr;
            bf16x8 v = {0, 0, 0, 0, 0, 0, 0, 0};
            if (srow < SS) {
                int tok = x[b * SS + srow];
                const float* ep = emb + (long)tok * EE + eh * 160 + c * 8;
                if (eh == 0 || c < 17) {
                    float4 f0 = ((const float4*)ep)[0];
                    float4 f1 = ((const float4*)ep)[1];
                    v[0] = f2bf(f0.x); v[1] = f2bf(f0.y); v[2] = f2bf(f0.z); v[3] = f2bf(f0.w);
                    v[4] = f2bf(f1.x); v[5] = f2bf(f1.y); v[6] = f2bf(f1.z); v[7] = f2bf(f1.w);
                } else if (c == 17) {  // elems 296..299 valid
                    float4 f0 = ((const float4*)ep)[0];
                    v[0] = f2bf(f0.x); v[1] = f2bf(f0.y); v[2] = f2bf(f0.z); v[3] = f2bf(f0.w);
                }
            }
            *(bf16x8*)&At[rr * LP + c * 8] = v;
        }
        __syncthreads();

        const unsigned short* bp = wsB + eh * HALFSZ + lane * 8;
        if (h2 == 0) {                 // primary g3 (base 255), secondary g0 (base 0)
            #pragma unroll 1
            for (int j = 0; j < 9;  ++j) do5<true >(lb, j, bp, 255, 0, acc);
            #pragma unroll 1
            for (int j = 9; j < 33; ++j) do5<false>(lb, j, bp, 255, 0, acc);
        } else {                       // primary g2 (base 130), secondary g1 (base 45)
            #pragma unroll 1
            for (int j = 0;  j < 17; ++j) do5<true >(lb, j, bp, 130, 45, acc);
            #pragma unroll 1
            for (int j = 17; j < 25; ++j) do5<false>(lb, j, bp, 130, 45, acc);
        }
    }

    // Epilogue: C/D col = lane&15 (filter within group), row = q*4 + reg.
    int gid[2]; gid[0] = h2 ? 2 : 3; gid[1] = h2 ? 1 : 0;
    #pragma unroll
    for (int t = 0; t < 3; ++t) {
        int tb = t0 + p * 48 + t * 16 + q * 4;
        #pragma unroll
        for (int u2 = 0; u2 < 2; ++u2) {
            int i  = gid[u2] * 16 + m;
            int ki = i / 2 + 2;
            int tmax = SS - ki;
            float bc = bconv[i];
            float mx = -3.0e38f;
            #pragma unroll
            for (int r = 0; r < 4; ++r) {
                float v = tanhf(acc[t][u2][r] + bc);
                if (tb + r <= tmax) mx = fmaxf(mx, v);
            }
            mx = fmaxf(mx, __shfl_xor(mx, 16));
            mx = fmaxf(mx, __shfl_xor(mx, 32));
            if (q == 0) wsF[(b * HH + i) * 36 + slice * 6 + p * 3 + t] = mx;
        }
    }
}

// ---- Kernel 3: max over 36 partials, linear, sigmoid. 128 blocks x 64 thr.
__global__ __launch_bounds__(64) void final_linear(const float* __restrict__ wsF,
                                                   const float* __restrict__ Wlin,
                                                   const float* __restrict__ blin,
                                                   float* __restrict__ out) {
    int b = blockIdx.x;
    int i = threadIdx.x;
    const float* pp = wsF + (b * HH + i) * 36;
    float mx = pp[0];
    #pragma unroll
    for (int j = 1; j < 36; ++j) mx = fmaxf(mx, pp[j]);
    float v = mx * Wlin[i];
    #pragma unroll
    for (int off = 1; off < 64; off <<= 1) v += __shfl_xor(v, off);
    if (i == 0) out[b] = 1.0f / (1.0f + expf(-(v + blin[0])));
}

extern "C" void kernel_launch(void* const* d_in, const int* in_sizes, int n_in,
                              void* d_out, int out_size, void* d_ws, size_t ws_size,
                              hipStream_t stream) {
    const int*   x     = (const int*)d_in[0];
    const float* emb   = (const float*)d_in[1];
    const float* Wconv = (const float*)d_in[2];
    const float* bconv = (const float*)d_in[3];
    const float* Wlin  = (const float*)d_in[4];
    const float* blin  = (const float*)d_in[5];
    float* out = (float*)d_out;

    unsigned short* wsB = (unsigned short*)d_ws;
    float*          wsF = (float*)((char*)d_ws + (1u << 20));

    prep_weights<<<1680, 256, 0, stream>>>(Wconv, wsB);
    conv_fused<<<768, 256, 0, stream>>>(x, emb, wsB, bconv, wsF);
    final_linear<<<128, 64, 0, stream>>>(wsF, Wlin, blin, out);
}